// Round 5
// baseline (2933.649 us; speedup 1.0000x reference)
//
#include <hip/hip_runtime.h>
#include <math.h>

typedef unsigned short u16;
typedef __attribute__((ext_vector_type(4))) float f32x4;
typedef __attribute__((ext_vector_type(4))) unsigned short u16x4;
typedef __attribute__((ext_vector_type(8))) short bf16x8;
typedef __attribute__((ext_vector_type(8))) unsigned short u16x8;

#define LOG2E 1.4426950408889634f

__device__ __forceinline__ u16 f2bf(float f) {
  union { float f; unsigned u; } v; v.f = f;
  unsigned r = (v.u + 0x7fff + ((v.u >> 16) & 1)) >> 16;
  return (u16)r;
}
__device__ __forceinline__ float bf2f(u16 u) {
  union { unsigned u; float f; } v; v.u = ((unsigned)u) << 16; return v.f;
}

__device__ __forceinline__ void stor(float* C, size_t i, float v) { C[i] = v; }
__device__ __forceinline__ void stor(u16* C, size_t i, float v) { C[i] = f2bf(v); }

// ---------------------------------------------------------------------------
// f32 -> bf16 conversion, 4 elems/thread.
// ---------------------------------------------------------------------------
__global__ void conv_f32_bf16(const float* __restrict__ src, u16* __restrict__ dst) {
  int i = (blockIdx.x * blockDim.x + threadIdx.x) * 4;
  f32x4 v = *(const f32x4*)(src + i);
  u16x4 o;
#pragma unroll
  for (int j = 0; j < 4; ++j) o[j] = f2bf(v[j]);
  *(u16x4*)(dst + i) = o;
}

// ---------------------------------------------------------------------------
// GEMM: C (MxN, TOUT row-major) = A (MxK bf16 row-major) * B^T (B: NxK bf16)
// m97 structure: 128x128 tile, BK=32, 4 waves (2x2), 4x4 16x16x32 frags/wave,
// global_load_lds width=16 into linear LDS. f32 accumulate; store f32 or bf16.
// ---------------------------------------------------------------------------
template <typename TOUT>
__global__ __launch_bounds__(256)
void gemm_bt(const u16* __restrict__ A, const u16* __restrict__ B,
             TOUT* __restrict__ C, int M, int N, int K) {
  __shared__ u16 lds_a[128 * 32];
  __shared__ u16 lds_b[128 * 32];
  const int tid  = threadIdx.x;
  const int lane = tid & 63;
  const int wid  = tid >> 6;
  const int wr = wid >> 1, wc = wid & 1;
  const int fr = lane & 15, fq = lane >> 4;
  const int row0 = blockIdx.x * 128, col0 = blockIdx.y * 128;
  const u16* ga = A + (size_t)row0 * K;
  const u16* gb = B + (size_t)col0 * K;
  f32x4 acc[4][4] = {};
  const int toff = tid * 16;  // byte offset within 8192B tile

  for (int k0 = 0; k0 < K; k0 += 32) {
#pragma unroll
    for (int i = 0; i < 2; ++i) {
      int off = i * 4096 + toff;
      int rr  = off >> 6;     // tile row (64B per row)
      int cb  = off & 63;     // byte within row
      __builtin_amdgcn_global_load_lds(
          (const __attribute__((address_space(1))) void*)((const char*)(ga + (size_t)rr * K + k0) + cb),
          (__attribute__((address_space(3))) void*)((char*)lds_a + off), 16, 0, 0);
      __builtin_amdgcn_global_load_lds(
          (const __attribute__((address_space(1))) void*)((const char*)(gb + (size_t)rr * K + k0) + cb),
          (__attribute__((address_space(3))) void*)((char*)lds_b + off), 16, 0, 0);
    }
    __syncthreads();
    bf16x8 af[4], bfv[4];
#pragma unroll
    for (int m = 0; m < 4; ++m)
      af[m] = *(const bf16x8*)&lds_a[(wr * 64 + m * 16 + fr) * 32 + fq * 8];
#pragma unroll
    for (int n = 0; n < 4; ++n)
      bfv[n] = *(const bf16x8*)&lds_b[(wc * 64 + n * 16 + fr) * 32 + fq * 8];
#pragma unroll
    for (int m = 0; m < 4; ++m)
#pragma unroll
      for (int n = 0; n < 4; ++n)
        acc[m][n] = __builtin_amdgcn_mfma_f32_16x16x32_bf16(af[m], bfv[n], acc[m][n], 0, 0, 0);
    __syncthreads();
  }

#pragma unroll
  for (int m = 0; m < 4; ++m)
#pragma unroll
    for (int n = 0; n < 4; ++n) {
      int row = row0 + wr * 64 + m * 16 + fq * 4;
      int col = col0 + wc * 64 + n * 16 + fr;
#pragma unroll
      for (int r = 0; r < 4; ++r)
        stor(C, (size_t)(row + r) * N + col, acc[m][n][r]);
    }
}

// ---------------------------------------------------------------------------
// RoPE in-place on q,k parts of qkv[s][t*2048 + h*128 + d], t in {0,1}, bf16.
// One thread = 8 bf16 = 4 rotary pairs.
// ---------------------------------------------------------------------------
__global__ void rope_qk(u16* qkv) {
  int idx = blockIdx.x * blockDim.x + threadIdx.x;
  int i4 = idx & 15;
  int h  = (idx >> 4) & 15;
  int t  = (idx >> 8) & 1;
  int s  = idx >> 9;
  u16* p = qkv + (size_t)s * 6144 + t * 2048 + h * 128 + i4 * 8;
  u16x8 v = *(const u16x8*)p;
  u16x8 w;
#pragma unroll
  for (int j = 0; j < 4; ++j) {
    int i = i4 * 4 + j;                       // pair index 0..63
    float inv = exp2f(-(float)i * 0.2076205059304601f);  // 10000^(-i/64)
    float ang = (float)s * inv;
    float sn, cs;
    sincosf(ang, &sn, &cs);
    float e = bf2f(v[2 * j]);
    float o = bf2f(v[2 * j + 1]);
    w[2 * j]     = f2bf(e * cs - o * sn);
    w[2 * j + 1] = f2bf(e * sn + o * cs);
  }
  *(u16x8*)p = w;
}

// ---------------------------------------------------------------------------
// Naive causal attention, bf16 in / bf16 out, f32 math.
// One wave per (q-row, head); lane owns 2 head-dims. Online softmax; l >= 1
// always => never 0/0. grid = (S/4, nH), block = 256 (4 waves).
// ---------------------------------------------------------------------------
__global__ __launch_bounds__(256)
void attn_naive(const u16* __restrict__ qkv, u16* __restrict__ ao) {
  const int lane = threadIdx.x & 63;
  const int w    = threadIdx.x >> 6;
  const int s    = blockIdx.x * 4 + w;
  const int h    = blockIdx.y;
  const int d0   = lane * 2;
  const float c1 = 0.08838834764831845f * LOG2E;  // 1/sqrt(128) * log2(e)

  const size_t qoff = (size_t)s * 6144 + h * 128 + d0;
  float q0 = bf2f(qkv[qoff]);
  float q1 = bf2f(qkv[qoff + 1]);

  float M = -1e30f, l = 0.f, a0 = 0.f, a1 = 0.f;
  for (int j = 0; j <= s; ++j) {
    const size_t koff = (size_t)j * 6144 + 2048 + h * 128 + d0;
    float part = q0 * bf2f(qkv[koff]) + q1 * bf2f(qkv[koff + 1]);
    part += __shfl_xor(part, 1, 64);
    part += __shfl_xor(part, 2, 64);
    part += __shfl_xor(part, 4, 64);
    part += __shfl_xor(part, 8, 64);
    part += __shfl_xor(part, 16, 64);
    part += __shfl_xor(part, 32, 64);
    float sc = part * c1;
    float Mn = fmaxf(M, sc);
    float corr = exp2f(M - Mn);
    float p = exp2f(sc - Mn);
    M = Mn;
    l = l * corr + p;
    const size_t voff = (size_t)j * 6144 + 4096 + h * 128 + d0;
    a0 = a0 * corr + p * bf2f(qkv[voff]);
    a1 = a1 * corr + p * bf2f(qkv[voff + 1]);
  }
  const size_t ooff = (size_t)s * 2048 + h * 128 + d0;
  ao[ooff]     = f2bf(a0 / l);
  ao[ooff + 1] = f2bf(a1 / l);
}

// ---------------------------------------------------------------------------
extern "C" void kernel_launch(void* const* d_in, const int* in_sizes, int n_in,
                              void* d_out, int out_size, void* d_ws, size_t ws_size,
                              hipStream_t stream) {
  const float* x     = (const float*)d_in[0];   // 2048 x 2048 f32
  const float* w_qkv = (const float*)d_in[1];   // 6144 x 2048 f32
  const float* w_out = (const float*)d_in[2];   // 2048 x 2048 f32
  float* out = (float*)d_out;                   // 2048 x 2048 f32  <-- the fix
  const int S = 2048, H = 2048, O3 = 6144;

  // workspace layout (u16 elements), peak 58.8 MB with aliasing:
  u16* qkv     = (u16*)d_ws;                    // S*O3 = 25.2 MB
  u16* x_bf    = qkv + (size_t)S * O3;          //  8.4 MB
  u16* wqkv_bf = x_bf + (size_t)S * H;          // 25.2 MB
  u16* ao      = x_bf;                          // alias (x_bf dead after GEMM1)
  u16* wout_bf = wqkv_bf;                       // alias (wqkv_bf dead after GEMM1)

  // 1. convert inputs to bf16
  conv_f32_bf16<<<(S * H) / 1024, 256, 0, stream>>>(x, x_bf);
  conv_f32_bf16<<<(O3 * H) / 1024, 256, 0, stream>>>(w_qkv, wqkv_bf);
  // 2. qkv = x @ w_qkv^T   (M=2048, N=6144, K=2048), bf16 out
  gemm_bt<u16><<<dim3(S / 128, O3 / 128), 256, 0, stream>>>(x_bf, wqkv_bf, qkv, S, O3, H);
  // 3. RoPE on q,k in place
  rope_qk<<<(S * 2 * 16 * 16) / 256, 256, 0, stream>>>(qkv);
  // 4. convert w_out (into region freed by GEMM1 completion)
  conv_f32_bf16<<<(S * H) / 1024, 256, 0, stream>>>(w_out, wout_bf);
  // 5. naive causal attention -> ao[s][h*128+d]
  attn_naive<<<dim3(S / 4, 16), 256, 0, stream>>>(qkv, ao);
  // 6. out = ao @ w_out^T   (M=2048, N=2048, K=2048), f32 out
  gemm_bt<float><<<dim3(S / 128, H / 128), 256, 0, stream>>>(ao, wout_bf, out, S, H, H);
}

// Round 6
// 354.098 us; speedup vs baseline: 8.2848x; 8.2848x over previous
//
#include <hip/hip_runtime.h>
#include <math.h>

typedef unsigned short u16;
typedef __attribute__((ext_vector_type(4))) float f32x4;
typedef __attribute__((ext_vector_type(4))) unsigned short u16x4;
typedef __attribute__((ext_vector_type(8))) short bf16x8;
typedef __attribute__((ext_vector_type(8))) unsigned short u16x8;

#define LOG2E 1.4426950408889634f

__device__ __forceinline__ u16 f2bf(float f) {
  union { float f; unsigned u; } v; v.f = f;
  unsigned r = (v.u + 0x7fff + ((v.u >> 16) & 1)) >> 16;
  return (u16)r;
}
__device__ __forceinline__ float bf2f(u16 u) {
  union { unsigned u; float f; } v; v.u = ((unsigned)u) << 16; return v.f;
}

__device__ __forceinline__ void stor(float* C, size_t i, float v) { C[i] = v; }
__device__ __forceinline__ void stor(u16* C, size_t i, float v) { C[i] = f2bf(v); }

// ---------------------------------------------------------------------------
// f32 -> bf16 conversion, 4 elems/thread.
// ---------------------------------------------------------------------------
__global__ void conv_f32_bf16(const float* __restrict__ src, u16* __restrict__ dst) {
  int i = (blockIdx.x * blockDim.x + threadIdx.x) * 4;
  f32x4 v = *(const f32x4*)(src + i);
  u16x4 o;
#pragma unroll
  for (int j = 0; j < 4; ++j) o[j] = f2bf(v[j]);
  *(u16x4*)(dst + i) = o;
}

// ---------------------------------------------------------------------------
// GEMM: C (MxN, TOUT row-major) = A (MxK bf16 row-major) * B^T (B: NxK bf16)
// m97 structure: 128x128 tile, BK=32, 4 waves (2x2), 4x4 16x16x32 frags/wave,
// global_load_lds width=16 into linear LDS. f32 accumulate.
// ---------------------------------------------------------------------------
template <typename TOUT>
__global__ __launch_bounds__(256)
void gemm_bt(const u16* __restrict__ A, const u16* __restrict__ B,
             TOUT* __restrict__ C, int M, int N, int K) {
  __shared__ u16 lds_a[128 * 32];
  __shared__ u16 lds_b[128 * 32];
  const int tid  = threadIdx.x;
  const int lane = tid & 63;
  const int wid  = tid >> 6;
  const int wr = wid >> 1, wc = wid & 1;
  const int fr = lane & 15, fq = lane >> 4;
  const int row0 = blockIdx.x * 128, col0 = blockIdx.y * 128;
  const u16* ga = A + (size_t)row0 * K;
  const u16* gb = B + (size_t)col0 * K;
  f32x4 acc[4][4] = {};
  const int toff = tid * 16;

  for (int k0 = 0; k0 < K; k0 += 32) {
#pragma unroll
    for (int i = 0; i < 2; ++i) {
      int off = i * 4096 + toff;
      int rr  = off >> 6;
      int cb  = off & 63;
      __builtin_amdgcn_global_load_lds(
          (const __attribute__((address_space(1))) void*)((const char*)(ga + (size_t)rr * K + k0) + cb),
          (__attribute__((address_space(3))) void*)((char*)lds_a + off), 16, 0, 0);
      __builtin_amdgcn_global_load_lds(
          (const __attribute__((address_space(1))) void*)((const char*)(gb + (size_t)rr * K + k0) + cb),
          (__attribute__((address_space(3))) void*)((char*)lds_b + off), 16, 0, 0);
    }
    __syncthreads();
    bf16x8 af[4], bfv[4];
#pragma unroll
    for (int m = 0; m < 4; ++m)
      af[m] = *(const bf16x8*)&lds_a[(wr * 64 + m * 16 + fr) * 32 + fq * 8];
#pragma unroll
    for (int n = 0; n < 4; ++n)
      bfv[n] = *(const bf16x8*)&lds_b[(wc * 64 + n * 16 + fr) * 32 + fq * 8];
#pragma unroll
    for (int m = 0; m < 4; ++m)
#pragma unroll
      for (int n = 0; n < 4; ++n)
        acc[m][n] = __builtin_amdgcn_mfma_f32_16x16x32_bf16(af[m], bfv[n], acc[m][n], 0, 0, 0);
    __syncthreads();
  }

#pragma unroll
  for (int m = 0; m < 4; ++m)
#pragma unroll
    for (int n = 0; n < 4; ++n) {
      int row = row0 + wr * 64 + m * 16 + fq * 4;
      int col = col0 + wc * 64 + n * 16 + fr;
#pragma unroll
      for (int r = 0; r < 4; ++r)
        stor(C, (size_t)(row + r) * N + col, acc[m][n][r]);
    }
}

// ---------------------------------------------------------------------------
// RoPE in-place on q,k parts of qkv[s][t*2048 + h*128 + d], bf16.
// ---------------------------------------------------------------------------
__global__ void rope_qk(u16* qkv) {
  int idx = blockIdx.x * blockDim.x + threadIdx.x;
  int i4 = idx & 15;
  int h  = (idx >> 4) & 15;
  int t  = (idx >> 8) & 1;
  int s  = idx >> 9;
  u16* p = qkv + (size_t)s * 6144 + t * 2048 + h * 128 + i4 * 8;
  u16x8 v = *(const u16x8*)p;
  u16x8 w;
#pragma unroll
  for (int j = 0; j < 4; ++j) {
    int i = i4 * 4 + j;
    float inv = exp2f(-(float)i * 0.2076205059304601f);  // 10000^(-i/64)
    float ang = (float)s * inv;
    float sn, cs;
    sincosf(ang, &sn, &cs);
    float e = bf2f(v[2 * j]);
    float o = bf2f(v[2 * j + 1]);
    w[2 * j]     = f2bf(e * cs - o * sn);
    w[2 * j + 1] = f2bf(e * sn + o * cs);
  }
  *(u16x8*)p = w;
}

// ---------------------------------------------------------------------------
// Transpose V: vt[(h*128+d)][s] = qkv[s][4096 + h*128 + d]
// ---------------------------------------------------------------------------
__global__ void transpose_v(const u16* __restrict__ qkv, u16* __restrict__ vt) {
  __shared__ u16 tile[32][33];
  int s0 = blockIdx.x * 32, c0 = blockIdx.y * 32;
  int tx = threadIdx.x & 31, ty = threadIdx.x >> 5;  // 32 x 8
#pragma unroll
  for (int i = ty; i < 32; i += 8)
    tile[i][tx] = qkv[(size_t)(s0 + i) * 6144 + 4096 + c0 + tx];
  __syncthreads();
#pragma unroll
  for (int i = ty; i < 32; i += 8)
    vt[(size_t)(c0 + i) * 2048 + s0 + tx] = tile[tx][i];
}

// ---------------------------------------------------------------------------
// Causal MFMA flash attention. Per wave: 32 q-rows, KVBLK=32, one head.
// grid = (32, 16 heads), block = 128 (2 waves).
// Wave 0 -> q-tile blockIdx.x, wave 1 -> q-tile 63-blockIdx.x (65 tiles/block).
// Fragment conventions identical to the hardware-verified gemm_bt:
//   arg0 lane l: row (l&15), k-slice (l>>4)*8;  D: row=(l>>4)*4+r, col=l&15.
// ---------------------------------------------------------------------------
__global__ __launch_bounds__(128)
void attn_fwd(const u16* __restrict__ qkv, const u16* __restrict__ vt,
              u16* __restrict__ o) {
  const int h = blockIdx.y;
  const int lane = threadIdx.x & 63;
  const int wid  = threadIdx.x >> 6;
  const int fr = lane & 15, fq = lane >> 4;
  const int tile = (wid == 0) ? (int)blockIdx.x : 63 - (int)blockIdx.x;
  const int q0 = tile * 32;
  const u16* Qb = qkv + h * 128;
  const u16* Kb = qkv + 2048 + h * 128;
  const u16* Vb = vt + (size_t)h * 128 * 2048;
  __shared__ u16 plds[2][32 * 32];

  bf16x8 qf[2][4];
#pragma unroll
  for (int m = 0; m < 2; ++m)
#pragma unroll
    for (int ks = 0; ks < 4; ++ks)
      qf[m][ks] = *(const bf16x8*)&Qb[(size_t)(q0 + m * 16 + fr) * 6144 + ks * 32 + fq * 8];

  f32x4 oacc[2][8] = {};
  float mrow[2][4], lrow[2][4];
#pragma unroll
  for (int m = 0; m < 2; ++m)
#pragma unroll
    for (int r = 0; r < 4; ++r) { mrow[m][r] = -1e30f; lrow[m][r] = 0.f; }

  const float c1 = 0.08838834764831845f * LOG2E;  // 1/sqrt(128) * log2(e)
  const int ntiles = tile + 1;

  for (int t = 0; t < ntiles; ++t) {
    const int kv0 = t * 32;
    bf16x8 kf[2][4];
#pragma unroll
    for (int n = 0; n < 2; ++n)
#pragma unroll
      for (int ks = 0; ks < 4; ++ks)
        kf[n][ks] = *(const bf16x8*)&Kb[(size_t)(kv0 + n * 16 + fr) * 6144 + ks * 32 + fq * 8];

    f32x4 sc[2][2] = {};
#pragma unroll
    for (int m = 0; m < 2; ++m)
#pragma unroll
      for (int n = 0; n < 2; ++n)
#pragma unroll
        for (int ks = 0; ks < 4; ++ks)
          sc[m][n] = __builtin_amdgcn_mfma_f32_16x16x32_bf16(qf[m][ks], kf[n][ks], sc[m][n], 0, 0, 0);

    const bool diag = (t == ntiles - 1);
#pragma unroll
    for (int m = 0; m < 2; ++m)
#pragma unroll
      for (int n = 0; n < 2; ++n)
#pragma unroll
        for (int r = 0; r < 4; ++r) {
          float x = sc[m][n][r] * c1;
          if (diag) {
            int qi = m * 16 + fq * 4 + r;   // local q-row (kv0 == q0 here)
            int ki = n * 16 + fr;
            if (ki > qi) x = -1e30f;
          }
          sc[m][n][r] = x;
        }

#pragma unroll
    for (int m = 0; m < 2; ++m) {
#pragma unroll
      for (int r = 0; r < 4; ++r) {
        float v = fmaxf(sc[m][0][r], sc[m][1][r]);
        v = fmaxf(v, __shfl_xor(v, 1, 64));
        v = fmaxf(v, __shfl_xor(v, 2, 64));
        v = fmaxf(v, __shfl_xor(v, 4, 64));
        v = fmaxf(v, __shfl_xor(v, 8, 64));
        float Mn = fmaxf(mrow[m][r], v);
        float corr = exp2f(mrow[m][r] - Mn);
        mrow[m][r] = Mn;
        float rs = 0.f;
#pragma unroll
        for (int n = 0; n < 2; ++n) {
          float p = exp2f(sc[m][n][r] - Mn);
          sc[m][n][r] = p;
          rs += p;
        }
        rs += __shfl_xor(rs, 1, 64);
        rs += __shfl_xor(rs, 2, 64);
        rs += __shfl_xor(rs, 4, 64);
        rs += __shfl_xor(rs, 8, 64);
        lrow[m][r] = lrow[m][r] * corr + rs;
#pragma unroll
        for (int db = 0; db < 8; ++db)
          oacc[m][db][r] *= corr;
      }
    }

    // P (f32 frags) -> per-wave LDS (bf16) -> PV A-operand layout
#pragma unroll
    for (int m = 0; m < 2; ++m)
#pragma unroll
      for (int n = 0; n < 2; ++n)
#pragma unroll
        for (int r = 0; r < 4; ++r)
          plds[wid][(m * 16 + fq * 4 + r) * 32 + n * 16 + fr] = f2bf(sc[m][n][r]);
    asm volatile("s_waitcnt lgkmcnt(0)" ::: "memory");

    bf16x8 pf[2];
#pragma unroll
    for (int m = 0; m < 2; ++m)
      pf[m] = *(const bf16x8*)&plds[wid][(m * 16 + fr) * 32 + fq * 8];

    bf16x8 vf[8];
#pragma unroll
    for (int db = 0; db < 8; ++db)
      vf[db] = *(const bf16x8*)&Vb[(size_t)(db * 16 + fr) * 2048 + kv0 + fq * 8];

#pragma unroll
    for (int m = 0; m < 2; ++m)
#pragma unroll
      for (int db = 0; db < 8; ++db)
        oacc[m][db] = __builtin_amdgcn_mfma_f32_16x16x32_bf16(pf[m], vf[db], oacc[m][db], 0, 0, 0);
  }

#pragma unroll
  for (int m = 0; m < 2; ++m)
#pragma unroll
    for (int db = 0; db < 8; ++db)
#pragma unroll
      for (int r = 0; r < 4; ++r) {
        int srow = q0 + m * 16 + fq * 4 + r;
        int col  = h * 128 + db * 16 + fr;
        o[(size_t)srow * 2048 + col] = f2bf(oacc[m][db][r] / lrow[m][r]);
      }
}

// ---------------------------------------------------------------------------
extern "C" void kernel_launch(void* const* d_in, const int* in_sizes, int n_in,
                              void* d_out, int out_size, void* d_ws, size_t ws_size,
                              hipStream_t stream) {
  const float* x     = (const float*)d_in[0];   // 2048 x 2048 f32
  const float* w_qkv = (const float*)d_in[1];   // 6144 x 2048 f32
  const float* w_out = (const float*)d_in[2];   // 2048 x 2048 f32
  float* out = (float*)d_out;                   // 2048 x 2048 f32
  const int S = 2048, H = 2048, O3 = 6144;

  // workspace (u16 elems), peak 58.8 MB with aliasing:
  u16* qkv     = (u16*)d_ws;                    // S*O3 = 25.2 MB
  u16* x_bf    = qkv + (size_t)S * O3;          //  8.4 MB
  u16* wqkv_bf = x_bf + (size_t)S * H;          // 25.2 MB
  u16* ao      = x_bf;                          // alias (x_bf dead after GEMM1)
  u16* vt      = wqkv_bf;                       // alias (wqkv_bf dead after GEMM1)
  u16* wout_bf = wqkv_bf + (size_t)H * S;       // alias, fits in wqkv_bf region

  // 1. convert inputs to bf16
  conv_f32_bf16<<<(S * H) / 1024, 256, 0, stream>>>(x, x_bf);
  conv_f32_bf16<<<(O3 * H) / 1024, 256, 0, stream>>>(w_qkv, wqkv_bf);
  // 2. qkv = x @ w_qkv^T   (M=2048, N=6144, K=2048)
  gemm_bt<u16><<<dim3(S / 128, O3 / 128), 256, 0, stream>>>(x_bf, wqkv_bf, qkv, S, O3, H);
  // 3. RoPE on q,k in place
  rope_qk<<<(S * 2 * 16 * 16) / 256, 256, 0, stream>>>(qkv);
  // 4. vt[h*128+d][s] = V   (into region freed after GEMM1)
  transpose_v<<<dim3(S / 32, H / 32), 256, 0, stream>>>(qkv, vt);
  // 5. convert w_out
  conv_f32_bf16<<<(S * H) / 1024, 256, 0, stream>>>(w_out, wout_bf);
  // 6. causal MFMA flash attention -> ao[s][h*128+d]
  attn_fwd<<<dim3(32, 16), 128, 0, stream>>>(qkv, vt, ao);
  // 7. out = ao @ w_out^T  (M=2048, N=2048, K=2048), f32 store
  gemm_bt<float><<<dim3(S / 128, H / 128), 256, 0, stream>>>(ao, wout_bf, out, S, H, H);
}

// Round 7
// 267.019 us; speedup vs baseline: 10.9867x; 1.3261x over previous
//
#include <hip/hip_runtime.h>
#include <math.h>

typedef unsigned short u16;
typedef __attribute__((ext_vector_type(4))) float f32x4;
typedef __attribute__((ext_vector_type(4))) unsigned short u16x4;
typedef __attribute__((ext_vector_type(8))) short bf16x8;
typedef __attribute__((ext_vector_type(8))) unsigned short u16x8;

#define LOG2E 1.4426950408889634f

__device__ __forceinline__ u16 f2bf(float f) {
  union { float f; unsigned u; } v; v.f = f;
  unsigned r = (v.u + 0x7fff + ((v.u >> 16) & 1)) >> 16;
  return (u16)r;
}
__device__ __forceinline__ float bf2f(u16 u) {
  union { unsigned u; float f; } v; v.u = ((unsigned)u) << 16; return v.f;
}

__device__ __forceinline__ void stor(float* C, size_t i, float v) { C[i] = v; }
__device__ __forceinline__ void stor(u16* C, size_t i, float v) { C[i] = f2bf(v); }

// ---------------------------------------------------------------------------
// f32 -> bf16 conversion, 4 elems/thread.
// ---------------------------------------------------------------------------
__global__ void conv_f32_bf16(const float* __restrict__ src, u16* __restrict__ dst) {
  int i = (blockIdx.x * blockDim.x + threadIdx.x) * 4;
  f32x4 v = *(const f32x4*)(src + i);
  u16x4 o;
#pragma unroll
  for (int j = 0; j < 4; ++j) o[j] = f2bf(v[j]);
  *(u16x4*)(dst + i) = o;
}

// ---------------------------------------------------------------------------
// GEMM: C (MxN, TOUT row-major) = A (MxK bf16 row-major) * B^T (B: NxK bf16)
// m97 structure: 128x128 tile, BK=32, 4 waves (2x2), 4x4 16x16x32 frags/wave.
// ---------------------------------------------------------------------------
template <typename TOUT>
__global__ __launch_bounds__(256)
void gemm_bt(const u16* __restrict__ A, const u16* __restrict__ B,
             TOUT* __restrict__ C, int M, int N, int K) {
  __shared__ u16 lds_a[128 * 32];
  __shared__ u16 lds_b[128 * 32];
  const int tid  = threadIdx.x;
  const int lane = tid & 63;
  const int wid  = tid >> 6;
  const int wr = wid >> 1, wc = wid & 1;
  const int fr = lane & 15, fq = lane >> 4;
  const int row0 = blockIdx.x * 128, col0 = blockIdx.y * 128;
  const u16* ga = A + (size_t)row0 * K;
  const u16* gb = B + (size_t)col0 * K;
  f32x4 acc[4][4] = {};
  const int toff = tid * 16;

  for (int k0 = 0; k0 < K; k0 += 32) {
#pragma unroll
    for (int i = 0; i < 2; ++i) {
      int off = i * 4096 + toff;
      int rr  = off >> 6;
      int cb  = off & 63;
      __builtin_amdgcn_global_load_lds(
          (const __attribute__((address_space(1))) void*)((const char*)(ga + (size_t)rr * K + k0) + cb),
          (__attribute__((address_space(3))) void*)((char*)lds_a + off), 16, 0, 0);
      __builtin_amdgcn_global_load_lds(
          (const __attribute__((address_space(1))) void*)((const char*)(gb + (size_t)rr * K + k0) + cb),
          (__attribute__((address_space(3))) void*)((char*)lds_b + off), 16, 0, 0);
    }
    __syncthreads();
    bf16x8 af[4], bfv[4];
#pragma unroll
    for (int m = 0; m < 4; ++m)
      af[m] = *(const bf16x8*)&lds_a[(wr * 64 + m * 16 + fr) * 32 + fq * 8];
#pragma unroll
    for (int n = 0; n < 4; ++n)
      bfv[n] = *(const bf16x8*)&lds_b[(wc * 64 + n * 16 + fr) * 32 + fq * 8];
#pragma unroll
    for (int m = 0; m < 4; ++m)
#pragma unroll
      for (int n = 0; n < 4; ++n)
        acc[m][n] = __builtin_amdgcn_mfma_f32_16x16x32_bf16(af[m], bfv[n], acc[m][n], 0, 0, 0);
    __syncthreads();
  }

#pragma unroll
  for (int m = 0; m < 4; ++m)
#pragma unroll
    for (int n = 0; n < 4; ++n) {
      int row = row0 + wr * 64 + m * 16 + fq * 4;
      int col = col0 + wc * 64 + n * 16 + fr;
#pragma unroll
      for (int r = 0; r < 4; ++r)
        stor(C, (size_t)(row + r) * N + col, acc[m][n][r]);
    }
}

// ---------------------------------------------------------------------------
// RoPE in-place on q,k parts of qkv[s][t*2048 + h*128 + d], bf16.
// ---------------------------------------------------------------------------
__global__ void rope_qk(u16* qkv) {
  int idx = blockIdx.x * blockDim.x + threadIdx.x;
  int i4 = idx & 15;
  int h  = (idx >> 4) & 15;
  int t  = (idx >> 8) & 1;
  int s  = idx >> 9;
  u16* p = qkv + (size_t)s * 6144 + t * 2048 + h * 128 + i4 * 8;
  u16x8 v = *(const u16x8*)p;
  u16x8 w;
#pragma unroll
  for (int j = 0; j < 4; ++j) {
    int i = i4 * 4 + j;
    float inv = exp2f(-(float)i * 0.2076205059304601f);  // 10000^(-i/64)
    float ang = (float)s * inv;
    float sn, cs;
    sincosf(ang, &sn, &cs);
    float e = bf2f(v[2 * j]);
    float o = bf2f(v[2 * j + 1]);
    w[2 * j]     = f2bf(e * cs - o * sn);
    w[2 * j + 1] = f2bf(e * sn + o * cs);
  }
  *(u16x8*)p = w;
}

// ---------------------------------------------------------------------------
// Transpose V: vt[(h*128+d)][s] = qkv[s][4096 + h*128 + d]
// ---------------------------------------------------------------------------
__global__ void transpose_v(const u16* __restrict__ qkv, u16* __restrict__ vt) {
  __shared__ u16 tile[32][33];
  int s0 = blockIdx.x * 32, c0 = blockIdx.y * 32;
  int tx = threadIdx.x & 31, ty = threadIdx.x >> 5;  // 32 x 8
#pragma unroll
  for (int i = ty; i < 32; i += 8)
    tile[i][tx] = qkv[(size_t)(s0 + i) * 6144 + 4096 + c0 + tx];
  __syncthreads();
#pragma unroll
  for (int i = ty; i < 32; i += 8)
    vt[(size_t)(c0 + i) * 2048 + s0 + tx] = tile[tx][i];
}

// ---------------------------------------------------------------------------
// Causal MFMA flash attention, split-KV.
// Block = 512 thr (8 waves): 2 q-tiles (blockIdx.x and 63-blockIdx.x, load-
// balanced pair) x 4 kv-split waves. Wave ksel handles kv-tiles t==ksel mod 4
// with its own online softmax; flash-merge via LDS at the end.
// grid = (32, 16 heads).
// Fragment conventions identical to the hardware-verified gemm_bt.
// ---------------------------------------------------------------------------
__global__ __launch_bounds__(512)
void attn_fwd(const u16* __restrict__ qkv, const u16* __restrict__ vt,
              u16* __restrict__ ao) {
  const int h    = blockIdx.y;
  const int tid  = threadIdx.x;
  const int lane = tid & 63;
  const int wid  = tid >> 6;       // 0..7
  const int qsel = wid >> 2;       // 0/1 -> which q-tile
  const int ksel = wid & 3;        // kv-split slot
  const int fr = lane & 15, fq = lane >> 4;
  const int tile = qsel ? 63 - (int)blockIdx.x : (int)blockIdx.x;
  const int q0 = tile * 32;
  const u16* Qb = qkv + h * 128;
  const u16* Kb = qkv + 2048 + h * 128;
  const u16* Vb = vt + (size_t)h * 128 * 2048;

  // plds (kv-loop phase) and Obuf (merge phase) alias; separated by barrier.
  __shared__ __align__(16) char smem[32768];
  u16 (*plds)[2048]     = (u16(*)[2048])smem;       // [8 waves][32*32]
  float (*Obuf)[32][128] = (float(*)[32][128])smem; // [2 qtiles][32][128]
  __shared__ float mls[2][4][32][2];                // [qtile][ksel][row][m,l]

  bf16x8 qf[2][4];
#pragma unroll
  for (int m = 0; m < 2; ++m)
#pragma unroll
    for (int ks = 0; ks < 4; ++ks)
      qf[m][ks] = *(const bf16x8*)&Qb[(size_t)(q0 + m * 16 + fr) * 6144 + ks * 32 + fq * 8];

  f32x4 oacc[2][8] = {};
  float mrow[2][4], lrow[2][4];
#pragma unroll
  for (int m = 0; m < 2; ++m)
#pragma unroll
    for (int r = 0; r < 4; ++r) { mrow[m][r] = -1e30f; lrow[m][r] = 0.f; }

  const float c1 = 0.08838834764831845f * LOG2E;  // 1/sqrt(128) * log2(e)

  for (int t = ksel; t <= tile; t += 4) {
    const int kv0 = t * 32;
    bf16x8 kf[2][4];
#pragma unroll
    for (int n = 0; n < 2; ++n)
#pragma unroll
      for (int ks = 0; ks < 4; ++ks)
        kf[n][ks] = *(const bf16x8*)&Kb[(size_t)(kv0 + n * 16 + fr) * 6144 + ks * 32 + fq * 8];

    f32x4 sc[2][2] = {};
#pragma unroll
    for (int m = 0; m < 2; ++m)
#pragma unroll
      for (int n = 0; n < 2; ++n)
#pragma unroll
        for (int ks = 0; ks < 4; ++ks)
          sc[m][n] = __builtin_amdgcn_mfma_f32_16x16x32_bf16(qf[m][ks], kf[n][ks], sc[m][n], 0, 0, 0);

    const bool diag = (t == tile);
#pragma unroll
    for (int m = 0; m < 2; ++m)
#pragma unroll
      for (int n = 0; n < 2; ++n)
#pragma unroll
        for (int r = 0; r < 4; ++r) {
          float x = sc[m][n][r] * c1;
          if (diag) {
            int qi = m * 16 + fq * 4 + r;   // local q-row (kv0 == q0 here)
            int ki = n * 16 + fr;
            if (ki > qi) x = -1e30f;
          }
          sc[m][n][r] = x;
        }

#pragma unroll
    for (int m = 0; m < 2; ++m) {
#pragma unroll
      for (int r = 0; r < 4; ++r) {
        float v = fmaxf(sc[m][0][r], sc[m][1][r]);
        v = fmaxf(v, __shfl_xor(v, 1, 64));
        v = fmaxf(v, __shfl_xor(v, 2, 64));
        v = fmaxf(v, __shfl_xor(v, 4, 64));
        v = fmaxf(v, __shfl_xor(v, 8, 64));
        float Mn = fmaxf(mrow[m][r], v);
        float corr = exp2f(mrow[m][r] - Mn);
        mrow[m][r] = Mn;
        float rs = 0.f;
#pragma unroll
        for (int n = 0; n < 2; ++n) {
          float p = exp2f(sc[m][n][r] - Mn);
          sc[m][n][r] = p;
          rs += p;
        }
        rs += __shfl_xor(rs, 1, 64);
        rs += __shfl_xor(rs, 2, 64);
        rs += __shfl_xor(rs, 4, 64);
        rs += __shfl_xor(rs, 8, 64);
        lrow[m][r] = lrow[m][r] * corr + rs;
#pragma unroll
        for (int db = 0; db < 8; ++db)
          oacc[m][db][r] *= corr;
      }
    }

    // P (f32 frags) -> per-wave LDS (bf16) -> PV A-operand layout
#pragma unroll
    for (int m = 0; m < 2; ++m)
#pragma unroll
      for (int n = 0; n < 2; ++n)
#pragma unroll
        for (int r = 0; r < 4; ++r)
          plds[wid][(m * 16 + fq * 4 + r) * 32 + n * 16 + fr] = f2bf(sc[m][n][r]);
    asm volatile("s_waitcnt lgkmcnt(0)" ::: "memory");

    bf16x8 pf[2];
#pragma unroll
    for (int m = 0; m < 2; ++m)
      pf[m] = *(const bf16x8*)&plds[wid][(m * 16 + fr) * 32 + fq * 8];

    bf16x8 vf[8];
#pragma unroll
    for (int db = 0; db < 8; ++db)
      vf[db] = *(const bf16x8*)&Vb[(size_t)(db * 16 + fr) * 2048 + kv0 + fq * 8];

#pragma unroll
    for (int m = 0; m < 2; ++m)
#pragma unroll
      for (int db = 0; db < 8; ++db)
        oacc[m][db] = __builtin_amdgcn_mfma_f32_16x16x32_bf16(pf[m], vf[db], oacc[m][db], 0, 0, 0);
  }

  // ---- flash merge across the 4 kv-split waves of each q-tile ----
  if (fr == 0) {
#pragma unroll
    for (int m = 0; m < 2; ++m)
#pragma unroll
      for (int r = 0; r < 4; ++r) {
        int row = m * 16 + fq * 4 + r;
        mls[qsel][ksel][row][0] = mrow[m][r];
        mls[qsel][ksel][row][1] = lrow[m][r];
      }
  }
  __syncthreads();   // also fences plds -> Obuf aliasing

  float scal[2][4];
#pragma unroll
  for (int m = 0; m < 2; ++m)
#pragma unroll
    for (int r = 0; r < 4; ++r) {
      int row = m * 16 + fq * 4 + r;
      float M = fmaxf(fmaxf(mls[qsel][0][row][0], mls[qsel][1][row][0]),
                      fmaxf(mls[qsel][2][row][0], mls[qsel][3][row][0]));
      scal[m][r] = exp2f(mrow[m][r] - M);   // 0 for idle waves (m=-1e30)
    }

  for (int w = 0; w < 4; ++w) {
    if (ksel == w) {
#pragma unroll
      for (int m = 0; m < 2; ++m)
#pragma unroll
        for (int db = 0; db < 8; ++db)
#pragma unroll
          for (int r = 0; r < 4; ++r) {
            int row = m * 16 + fq * 4 + r;
            int col = db * 16 + fr;
            float v = oacc[m][db][r] * scal[m][r];
            if (w == 0) Obuf[qsel][row][col] = v;
            else        Obuf[qsel][row][col] += v;
          }
    }
    __syncthreads();
  }

  // write-out: wave (qsel,ksel) normalizes+stores rows ksel*8 .. ksel*8+7
#pragma unroll
  for (int rr = 0; rr < 8; ++rr) {
    int row = ksel * 8 + rr;
    float M = fmaxf(fmaxf(mls[qsel][0][row][0], mls[qsel][1][row][0]),
                    fmaxf(mls[qsel][2][row][0], mls[qsel][3][row][0]));
    float lt = 0.f;
#pragma unroll
    for (int w2 = 0; w2 < 4; ++w2)
      lt += exp2f(mls[qsel][w2][row][0] - M) * mls[qsel][w2][row][1];
    float inv = 1.0f / lt;
    float v0 = Obuf[qsel][row][lane * 2]     * inv;
    float v1 = Obuf[qsel][row][lane * 2 + 1] * inv;
    unsigned pack = (unsigned)f2bf(v0) | ((unsigned)f2bf(v1) << 16);
    *(unsigned*)&ao[(size_t)(q0 + row) * 2048 + h * 128 + lane * 2] = pack;
  }
}

// ---------------------------------------------------------------------------
extern "C" void kernel_launch(void* const* d_in, const int* in_sizes, int n_in,
                              void* d_out, int out_size, void* d_ws, size_t ws_size,
                              hipStream_t stream) {
  const float* x     = (const float*)d_in[0];   // 2048 x 2048 f32
  const float* w_qkv = (const float*)d_in[1];   // 6144 x 2048 f32
  const float* w_out = (const float*)d_in[2];   // 2048 x 2048 f32
  float* out = (float*)d_out;                   // 2048 x 2048 f32
  const int S = 2048, H = 2048, O3 = 6144;

  // workspace (u16 elems), peak 58.8 MB with aliasing:
  u16* qkv     = (u16*)d_ws;                    // S*O3 = 25.2 MB
  u16* x_bf    = qkv + (size_t)S * O3;          //  8.4 MB
  u16* wqkv_bf = x_bf + (size_t)S * H;          // 25.2 MB
  u16* ao      = x_bf;                          // alias (x_bf dead after GEMM1)
  u16* vt      = wqkv_bf;                       // alias (wqkv_bf dead after GEMM1)
  u16* wout_bf = wqkv_bf + (size_t)H * S;       // alias, fits in wqkv_bf region

  // 1. convert inputs to bf16
  conv_f32_bf16<<<(S * H) / 1024, 256, 0, stream>>>(x, x_bf);
  conv_f32_bf16<<<(O3 * H) / 1024, 256, 0, stream>>>(w_qkv, wqkv_bf);
  // 2. qkv = x @ w_qkv^T   (M=2048, N=6144, K=2048)
  gemm_bt<u16><<<dim3(S / 128, O3 / 128), 256, 0, stream>>>(x_bf, wqkv_bf, qkv, S, O3, H);
  // 3. RoPE on q,k in place
  rope_qk<<<(S * 2 * 16 * 16) / 256, 256, 0, stream>>>(qkv);
  // 4. vt[h*128+d][s] = V   (into region freed after GEMM1)
  transpose_v<<<dim3(S / 32, H / 32), 256, 0, stream>>>(qkv, vt);
  // 5. convert w_out
  conv_f32_bf16<<<(S * H) / 1024, 256, 0, stream>>>(w_out, wout_bf);
  // 6. causal MFMA flash attention (split-KV) -> ao[s][h*128+d]
  attn_fwd<<<dim3(32, 16), 512, 0, stream>>>(qkv, vt, ao);
  // 7. out = ao @ w_out^T  (M=2048, N=2048, K=2048), f32 store
  gemm_bt<float><<<dim3(S / 128, H / 128), 256, 0, stream>>>(ao, wout_bf, out, S, H, H);
}

// Round 8
// 234.926 us; speedup vs baseline: 12.4875x; 1.1366x over previous
//
#include <hip/hip_runtime.h>
#include <math.h>

typedef unsigned short u16;
typedef __attribute__((ext_vector_type(4))) float f32x4;
typedef __attribute__((ext_vector_type(16))) float f32x16;
typedef __attribute__((ext_vector_type(4))) unsigned short u16x4;
typedef __attribute__((ext_vector_type(8))) short bf16x8;
typedef __attribute__((ext_vector_type(8))) unsigned short u16x8;

#define LOG2E 1.4426950408889634f

__device__ __forceinline__ u16 f2bf(float f) {
  union { float f; unsigned u; } v; v.f = f;
  unsigned r = (v.u + 0x7fff + ((v.u >> 16) & 1)) >> 16;
  return (u16)r;
}
__device__ __forceinline__ float bf2f(u16 u) {
  union { unsigned u; float f; } v; v.u = ((unsigned)u) << 16; return v.f;
}
__device__ __forceinline__ void stor(float* C, size_t i, float v) { C[i] = v; }
__device__ __forceinline__ void stor(u16* C, size_t i, float v) { C[i] = f2bf(v); }

// packed f32x2 -> bf16x2 (dst.lo = bf16(a), dst.hi = bf16(b))
__device__ __forceinline__ unsigned cvtpk(float a, float b) {
  unsigned r;
  asm("v_cvt_pk_bf16_f32 %0, %1, %2" : "=v"(r) : "v"(a), "v"(b));
  return r;
}
// swap: a.hi-lanes <-> b.lo-lanes.  After: a[i>=32]=b_old[i-32], b[i<32]=a_old[i+32]
__device__ __forceinline__ void plswap(unsigned &a, unsigned &b) {
  asm volatile("v_permlane32_swap_b32 %0, %1" : "+v"(a), "+v"(b));
}

// ---------------------------------------------------------------------------
// f32 -> bf16 conversion, 4 elems/thread.
// ---------------------------------------------------------------------------
__global__ void conv_f32_bf16(const float* __restrict__ src, u16* __restrict__ dst) {
  int i = (blockIdx.x * blockDim.x + threadIdx.x) * 4;
  f32x4 v = *(const f32x4*)(src + i);
  u16x4 o;
#pragma unroll
  for (int j = 0; j < 4; ++j) o[j] = f2bf(v[j]);
  *(u16x4*)(dst + i) = o;
}

// ---------------------------------------------------------------------------
// GEMM: C (MxN, TOUT row-major) = A (MxK bf16 row-major) * B^T (B: NxK bf16)
// m97 structure: 128x128 tile, BK=32, 4 waves (2x2), 4x4 16x16x32 frags/wave.
// ---------------------------------------------------------------------------
template <typename TOUT>
__global__ __launch_bounds__(256)
void gemm_bt(const u16* __restrict__ A, const u16* __restrict__ B,
             TOUT* __restrict__ C, int M, int N, int K) {
  __shared__ u16 lds_a[128 * 32];
  __shared__ u16 lds_b[128 * 32];
  const int tid  = threadIdx.x;
  const int lane = tid & 63;
  const int wid  = tid >> 6;
  const int wr = wid >> 1, wc = wid & 1;
  const int fr = lane & 15, fq = lane >> 4;
  const int row0 = blockIdx.x * 128, col0 = blockIdx.y * 128;
  const u16* ga = A + (size_t)row0 * K;
  const u16* gb = B + (size_t)col0 * K;
  f32x4 acc[4][4] = {};
  const int toff = tid * 16;

  for (int k0 = 0; k0 < K; k0 += 32) {
#pragma unroll
    for (int i = 0; i < 2; ++i) {
      int off = i * 4096 + toff;
      int rr  = off >> 6;
      int cb  = off & 63;
      __builtin_amdgcn_global_load_lds(
          (const __attribute__((address_space(1))) void*)((const char*)(ga + (size_t)rr * K + k0) + cb),
          (__attribute__((address_space(3))) void*)((char*)lds_a + off), 16, 0, 0);
      __builtin_amdgcn_global_load_lds(
          (const __attribute__((address_space(1))) void*)((const char*)(gb + (size_t)rr * K + k0) + cb),
          (__attribute__((address_space(3))) void*)((char*)lds_b + off), 16, 0, 0);
    }
    __syncthreads();
    bf16x8 af[4], bfv[4];
#pragma unroll
    for (int m = 0; m < 4; ++m)
      af[m] = *(const bf16x8*)&lds_a[(wr * 64 + m * 16 + fr) * 32 + fq * 8];
#pragma unroll
    for (int n = 0; n < 4; ++n)
      bfv[n] = *(const bf16x8*)&lds_b[(wc * 64 + n * 16 + fr) * 32 + fq * 8];
#pragma unroll
    for (int m = 0; m < 4; ++m)
#pragma unroll
      for (int n = 0; n < 4; ++n)
        acc[m][n] = __builtin_amdgcn_mfma_f32_16x16x32_bf16(af[m], bfv[n], acc[m][n], 0, 0, 0);
    __syncthreads();
  }

#pragma unroll
  for (int m = 0; m < 4; ++m)
#pragma unroll
    for (int n = 0; n < 4; ++n) {
      int row = row0 + wr * 64 + m * 16 + fq * 4;
      int col = col0 + wc * 64 + n * 16 + fr;
#pragma unroll
      for (int r = 0; r < 4; ++r)
        stor(C, (size_t)(row + r) * N + col, acc[m][n][r]);
    }
}

// ---------------------------------------------------------------------------
// RoPE in-place on q,k parts of qkv[s][t*2048 + h*128 + d], bf16.
// ---------------------------------------------------------------------------
__global__ void rope_qk(u16* qkv) {
  int idx = blockIdx.x * blockDim.x + threadIdx.x;
  int i4 = idx & 15;
  int h  = (idx >> 4) & 15;
  int t  = (idx >> 8) & 1;
  int s  = idx >> 9;
  u16* p = qkv + (size_t)s * 6144 + t * 2048 + h * 128 + i4 * 8;
  u16x8 v = *(const u16x8*)p;
  u16x8 w;
#pragma unroll
  for (int j = 0; j < 4; ++j) {
    int i = i4 * 4 + j;
    float inv = exp2f(-(float)i * 0.2076205059304601f);  // 10000^(-i/64)
    float ang = (float)s * inv;
    float sn, cs;
    sincosf(ang, &sn, &cs);
    float e = bf2f(v[2 * j]);
    float o = bf2f(v[2 * j + 1]);
    w[2 * j]     = f2bf(e * cs - o * sn);
    w[2 * j + 1] = f2bf(e * sn + o * cs);
  }
  *(u16x8*)p = w;
}

// ---------------------------------------------------------------------------
// Transpose V: vt[(h*128+d)][s] = qkv[s][4096 + h*128 + d]
// ---------------------------------------------------------------------------
__global__ void transpose_v(const u16* __restrict__ qkv, u16* __restrict__ vt) {
  __shared__ u16 tile[32][33];
  int s0 = blockIdx.x * 32, c0 = blockIdx.y * 32;
  int tx = threadIdx.x & 31, ty = threadIdx.x >> 5;  // 32 x 8
#pragma unroll
  for (int i = ty; i < 32; i += 8)
    tile[i][tx] = qkv[(size_t)(s0 + i) * 6144 + 4096 + c0 + tx];
  __syncthreads();
#pragma unroll
  for (int i = ty; i < 32; i += 8)
    vt[(size_t)(c0 + i) * 2048 + s0 + tx] = tile[tx][i];
}

// ---------------------------------------------------------------------------
// Causal flash attention, split-KV, 32x32 MFMA, swapped QK^T.
// Block = 512 thr (8 waves): 2 q-tiles (blockIdx.x, 63-blockIdx.x) x 4 kv-
// split waves (t == ksel mod 4). grid = (32, 16 heads).
// S = mfma(K,Q): S[kv][q], q = lane&31 (per-lane softmax, 2 shuffles/tile).
// P -> PV A-frags via v_cvt_pk_bf16_f32 + v_permlane32_swap_b32 (no LDS).
// O = mfma(P,V^T): O[q=reg][d=lane]. T13 defer-max (THR=8, log2 domain).
// ---------------------------------------------------------------------------
__global__ __launch_bounds__(512)
void attn_fwd(const u16* __restrict__ qkv, const u16* __restrict__ vt,
              u16* __restrict__ ao) {
  const int h    = blockIdx.y;
  const int tid  = threadIdx.x;
  const int lane = tid & 63;
  const int wid  = tid >> 6;       // 0..7
  const int qsel = wid >> 2;       // which q-tile
  const int ksel = wid & 3;        // kv-split slot
  const int l31  = lane & 31;
  const int hh   = lane >> 5;
  const int tile = qsel ? 63 - (int)blockIdx.x : (int)blockIdx.x;
  const int q0 = tile * 32;
  const u16* Qb = qkv + h * 128;
  const u16* Kb = qkv + 2048 + h * 128;
  const u16* Vb = vt + (size_t)h * 128 * 2048;

  __shared__ float Obuf[2][32][128];   // 32 KB (merge phase)
  __shared__ float mls[2][4][32][2];   // per-wave (m, l) per q-row
  __shared__ float corrb[2][4][32];    // rescale bounce (rarely used)

  f32x16 oacc[4] = {};                 // [d-chunk][reg]; q=(r&3)+8*(r>>2)+4*hh, d=32c+l31
  float M = -1e30f, L = 0.f;
  const float c1 = 0.08838834764831845f * LOG2E;  // 1/sqrt(128) * log2(e)

  const size_t qrow = (size_t)(q0 + l31) * 6144;

  for (int t = ksel; t <= tile; t += 4) {
    const int kv0 = t * 32;
    const size_t krow = (size_t)(kv0 + l31) * 6144;
    f32x16 sc = {};
    // QK^T swapped: A = K rows, B = Q rows; two 4-slice batches
    {
      bf16x8 kf[4], qf[4];
#pragma unroll
      for (int s = 0; s < 4; ++s) {
        kf[s] = *(const bf16x8*)&Kb[krow + s * 16 + hh * 8];
        qf[s] = *(const bf16x8*)&Qb[qrow + s * 16 + hh * 8];
      }
#pragma unroll
      for (int s = 0; s < 4; ++s)
        sc = __builtin_amdgcn_mfma_f32_32x32x16_bf16(kf[s], qf[s], sc, 0, 0, 0);
#pragma unroll
      for (int s = 0; s < 4; ++s) {
        kf[s] = *(const bf16x8*)&Kb[krow + (s + 4) * 16 + hh * 8];
        qf[s] = *(const bf16x8*)&Qb[qrow + (s + 4) * 16 + hh * 8];
      }
#pragma unroll
      for (int s = 0; s < 4; ++s)
        sc = __builtin_amdgcn_mfma_f32_32x32x16_bf16(kf[s], qf[s], sc, 0, 0, 0);
    }
    // V fragments issued before softmax (latency overlap)
    bf16x8 vf[4][2];
#pragma unroll
    for (int c = 0; c < 4; ++c)
#pragma unroll
      for (int tt = 0; tt < 2; ++tt)
        vf[c][tt] = *(const bf16x8*)&Vb[(size_t)(32 * c + l31) * 2048 + kv0 + tt * 16 + hh * 8];

    // scale + causal mask (S[kv][q]: q = l31, kv = (r&3)+8*(r>>2)+4*hh)
    if (t == tile) {
#pragma unroll
      for (int r = 0; r < 16; ++r) {
        int kv = (r & 3) + 8 * (r >> 2) + 4 * hh;
        sc[r] = (kv > l31) ? -1e30f : sc[r] * c1;
      }
    } else {
#pragma unroll
      for (int r = 0; r < 16; ++r) sc[r] *= c1;
    }

    // per-lane (per-q) online softmax
    float pm = fmaxf(fmaxf(fmaxf(sc[0], sc[1]), fmaxf(sc[2], sc[3])),
                     fmaxf(fmaxf(sc[4], sc[5]), fmaxf(sc[6], sc[7])));
    float pm2 = fmaxf(fmaxf(fmaxf(sc[8], sc[9]), fmaxf(sc[10], sc[11])),
                      fmaxf(fmaxf(sc[12], sc[13]), fmaxf(sc[14], sc[15])));
    pm = fmaxf(pm, pm2);
    pm = fmaxf(pm, __shfl_xor(pm, 32, 64));

    bool defer = (pm <= M + 8.0f);     // T13: P bounded by 2^8
    if (!__all(defer)) {
      float Mn = fmaxf(M, pm);
      float corr = exp2f(M - Mn);
      M = Mn;
      L *= corr;
      if (hh == 0) corrb[qsel][ksel][l31] = corr;
      asm volatile("s_waitcnt lgkmcnt(0)" ::: "memory");
#pragma unroll
      for (int r = 0; r < 16; ++r) {
        int qr = (r & 3) + 8 * (r >> 2) + 4 * hh;
        float cr = corrb[qsel][ksel][qr];
#pragma unroll
        for (int c = 0; c < 4; ++c) oacc[c][r] *= cr;
      }
    }

#pragma unroll
    for (int r = 0; r < 16; ++r) sc[r] = exp2f(sc[r] - M);
    float rs = ((sc[0] + sc[1]) + (sc[2] + sc[3])) + ((sc[4] + sc[5]) + (sc[6] + sc[7]))
             + ((sc[8] + sc[9]) + (sc[10] + sc[11])) + ((sc[12] + sc[13]) + (sc[14] + sc[15]));
    rs += __shfl_xor(rs, 32, 64);
    L += rs;

    // pack P into PV A-frags (kv-slice per lane) and accumulate O
#pragma unroll
    for (int tt = 0; tt < 2; ++tt) {
      unsigned A0 = cvtpk(sc[8 * tt + 0], sc[8 * tt + 1]);
      unsigned A1 = cvtpk(sc[8 * tt + 2], sc[8 * tt + 3]);
      unsigned B0 = cvtpk(sc[8 * tt + 4], sc[8 * tt + 5]);
      unsigned B1 = cvtpk(sc[8 * tt + 6], sc[8 * tt + 7]);
      plswap(A0, B0);
      plswap(A1, B1);
      union { unsigned w[4]; bf16x8 v; } pa;
      pa.w[0] = A0; pa.w[1] = A1; pa.w[2] = B0; pa.w[3] = B1;
#pragma unroll
      for (int c = 0; c < 4; ++c)
        oacc[c] = __builtin_amdgcn_mfma_f32_32x32x16_bf16(pa.v, vf[c][tt], oacc[c], 0, 0, 0);
    }
  }

  // ---- flash merge across the 4 kv-split waves of each q-tile ----
  if (hh == 0) { mls[qsel][ksel][l31][0] = M; mls[qsel][ksel][l31][1] = L; }
  __syncthreads();

  for (int w = 0; w < 4; ++w) {
    if (ksel == w) {
#pragma unroll
      for (int r = 0; r < 16; ++r) {
        int q = (r & 3) + 8 * (r >> 2) + 4 * hh;
        float m_own = mls[qsel][ksel][q][0];
        float Mg = fmaxf(fmaxf(mls[qsel][0][q][0], mls[qsel][1][q][0]),
                         fmaxf(mls[qsel][2][q][0], mls[qsel][3][q][0]));
        float s = exp2f(m_own - Mg);
#pragma unroll
        for (int c = 0; c < 4; ++c) {
          float v = oacc[c][r] * s;
          if (w == 0) Obuf[qsel][q][32 * c + l31] = v;
          else        Obuf[qsel][q][32 * c + l31] += v;
        }
      }
    }
    __syncthreads();
  }

  // write-out: wave (qsel,ksel) normalizes+stores rows ksel*8 .. ksel*8+7
#pragma unroll
  for (int rr = 0; rr < 8; ++rr) {
    int row = ksel * 8 + rr;
    float Mg = fmaxf(fmaxf(mls[qsel][0][row][0], mls[qsel][1][row][0]),
                     fmaxf(mls[qsel][2][row][0], mls[qsel][3][row][0]));
    float lt = 0.f;
#pragma unroll
    for (int w2 = 0; w2 < 4; ++w2)
      lt += exp2f(mls[qsel][w2][row][0] - Mg) * mls[qsel][w2][row][1];
    float inv = 1.0f / lt;
    float v0 = Obuf[qsel][row][lane * 2]     * inv;
    float v1 = Obuf[qsel][row][lane * 2 + 1] * inv;
    unsigned pack = (unsigned)f2bf(v0) | ((unsigned)f2bf(v1) << 16);
    *(unsigned*)&ao[(size_t)(q0 + row) * 2048 + h * 128 + lane * 2] = pack;
  }
}

// ---------------------------------------------------------------------------
extern "C" void kernel_launch(void* const* d_in, const int* in_sizes, int n_in,
                              void* d_out, int out_size, void* d_ws, size_t ws_size,
                              hipStream_t stream) {
  const float* x     = (const float*)d_in[0];   // 2048 x 2048 f32
  const float* w_qkv = (const float*)d_in[1];   // 6144 x 2048 f32
  const float* w_out = (const float*)d_in[2];   // 2048 x 2048 f32
  float* out = (float*)d_out;                   // 2048 x 2048 f32
  const int S = 2048, H = 2048, O3 = 6144;

  // workspace (u16 elems), peak 58.8 MB with aliasing:
  u16* qkv     = (u16*)d_ws;                    // S*O3 = 25.2 MB
  u16* x_bf    = qkv + (size_t)S * O3;          //  8.4 MB
  u16* wqkv_bf = x_bf + (size_t)S * H;          // 25.2 MB
  u16* ao      = x_bf;                          // alias (x_bf dead after GEMM1)
  u16* vt      = wqkv_bf;                       // alias (wqkv_bf dead after GEMM1)
  u16* wout_bf = wqkv_bf + (size_t)H * S;       // alias, fits in wqkv_bf region

  // 1. convert inputs to bf16
  conv_f32_bf16<<<(S * H) / 1024, 256, 0, stream>>>(x, x_bf);
  conv_f32_bf16<<<(O3 * H) / 1024, 256, 0, stream>>>(w_qkv, wqkv_bf);
  // 2. qkv = x @ w_qkv^T   (M=2048, N=6144, K=2048)
  gemm_bt<u16><<<dim3(S / 128, O3 / 128), 256, 0, stream>>>(x_bf, wqkv_bf, qkv, S, O3, H);
  // 3. RoPE on q,k in place
  rope_qk<<<(S * 2 * 16 * 16) / 256, 256, 0, stream>>>(qkv);
  // 4. vt[h*128+d][s] = V   (into region freed after GEMM1)
  transpose_v<<<dim3(S / 32, H / 32), 256, 0, stream>>>(qkv, vt);
  // 5. convert w_out
  conv_f32_bf16<<<(S * H) / 1024, 256, 0, stream>>>(w_out, wout_bf);
  // 6. causal flash attention (split-KV, 32x32) -> ao[s][h*128+d]
  attn_fwd<<<dim3(32, 16), 512, 0, stream>>>(qkv, vt, ao);
  // 7. out = ao @ w_out^T  (M=2048, N=2048, K=2048), f32 store
  gemm_bt<float><<<dim3(S / 128, H / 128), 256, 0, stream>>>(ao, wout_bf, out, S, H, H);
}